// Round 1
// 315.103 us; speedup vs baseline: 1.0944x; 1.0944x over previous
//
#include <hip/hip_runtime.h>
#include <stdint.h>

typedef __attribute__((ext_vector_type(8))) short short8;
typedef __attribute__((ext_vector_type(4))) float f32x4;
typedef __attribute__((ext_vector_type(16))) float f32x16;
typedef __attribute__((ext_vector_type(4))) unsigned uint4v;

#define LOG2E 1.4426950408889634f

__device__ __forceinline__ unsigned short f2bf(float f) {
    unsigned u = __float_as_uint(f);
    unsigned r = u + 0x7fffu + ((u >> 16) & 1u);   // RNE
    return (unsigned short)(r >> 16);
}
// monotone float<->uint encoding for atomicMax on floats
__device__ __forceinline__ unsigned fenc(float f) {
    unsigned u = __float_as_uint(f);
    return (u & 0x80000000u) ? ~u : (u | 0x80000000u);
}
__device__ __forceinline__ float fdec(unsigned e) {
    unsigned u = (e & 0x80000000u) ? (e & 0x7fffffffu) : ~e;
    return __uint_as_float(u);
}
__device__ __forceinline__ unsigned cvt_pk_bf16(float lo, float hi) {
    unsigned r;
    asm("v_cvt_pk_bf16_f32 %0, %1, %2" : "=v"(r) : "v"(lo), "v"(hi));
    return r;
}

// ---- fused setup: pack adj, copy x, W -> bf16 W^T, init s2 max slots --------
__global__ __launch_bounds__(256) void k_setup(
    const float* __restrict__ xin, const float* __restrict__ Wf,
    const int* __restrict__ adj, float* __restrict__ xq,
    unsigned short* __restrict__ wTb, unsigned* __restrict__ s2mx,
    unsigned long long* __restrict__ packed)
{
    int blk = blockIdx.x, tid = threadIdx.x;
    if (blk < 2048) {                                 // pack adj -> bitmask
        int w = (blk * 256 + tid) >> 6;               // global wave id, 8192 waves
        int lane = tid & 63;
        for (int k = 0; k < 64; k++) {
            int q = w * 64 + k;                       // word index 0..524287
            int row = q >> 5, wd = q & 31;
            int v = adj[row * 2048 + wd * 64 + lane];
            unsigned long long m = __ballot(v > 0);
            if (lane == 0) packed[q] = m;
        }
    } else if (blk < 4096) {                          // x -> running fp32 x
        int e0 = ((blk - 2048) * 256 + tid) * 4;
        *(f32x4*)(xq + e0) = *(const f32x4*)(xin + e0);
    } else if (blk < 4288) {                          // W -> bf16 W^T
        int c = (blk - 4096) * 256 + tid;             // < 49152
        int l = c >> 14, rem = c & 16383, n = rem >> 7, k = rem & 127;
        wTb[c] = f2bf(Wf[l * 16384 + k * 128 + n]);   // wTb[l][n][k] = W[l][k][n]
    } else if (tid < 24) {
        s2mx[tid] = fenc(-3e38f);
    }
}

// ---- per layer: h = relu(x@W+b) via bf16 MFMA; s1,s2 (scaled by log2e);
// batch max; hP packed. 512 threads: 4 row-groups x 2 col-halves.
// hP[b][t][jt][lane][8]: element = h[j = jt*16 + (lane>>5)*8 + i][d = t*32 + (lane&31)]
__global__ __launch_bounds__(512) void k_h(
    const float* __restrict__ xq, const unsigned short* __restrict__ wTb,
    const float* __restrict__ bF, const float* __restrict__ aF, int layer,
    unsigned short* __restrict__ hP, float* __restrict__ s1g,
    float* __restrict__ s2g, unsigned* __restrict__ s2mx)
{
    __shared__ short xs[64 * 136];    // x tile bf16
    __shared__ short wsb[128 * 136];  // W^T tile bf16; reused as transpose buffer
    __shared__ float s12[2][2][64];   // [s1/s2][colhalf][row] partials
    int blk = blockIdx.x, tid = threadIdx.x;
    int b = blk & 7, rg = blk >> 3;                   // XCD swizzle: batch = blk%8
    int row0 = b * 2048 + rg * 64;
    int lane = tid & 63, quad = lane >> 4, l15 = lane & 15;
    int wv = tid >> 6, rw = wv & 3, ch = wv >> 2;

    for (int c = tid; c < 1024; c += 512) {           // x: 64 rows x 128 k
        int r = c >> 4, kg = c & 15;
        const float* src = &xq[(row0 + r) * 128 + kg * 8];
        f32x4 v0 = *(const f32x4*)src;
        f32x4 v1 = *(const f32x4*)(src + 4);
        short8 o;
        o[0] = (short)f2bf(v0[0]); o[1] = (short)f2bf(v0[1]);
        o[2] = (short)f2bf(v0[2]); o[3] = (short)f2bf(v0[3]);
        o[4] = (short)f2bf(v1[0]); o[5] = (short)f2bf(v1[1]);
        o[6] = (short)f2bf(v1[2]); o[7] = (short)f2bf(v1[3]);
        *(short8*)&xs[r * 136 + kg * 8] = o;
    }
    const unsigned short* wl = wTb + layer * 16384;
    for (int c = tid; c < 2048; c += 512) {           // W^T: 128 n x 128 k
        int n = c >> 4, kg = c & 15;
        *(short8*)&wsb[n * 136 + kg * 8] = *(const short8*)&wl[n * 128 + kg * 8];
    }
    __syncthreads();

    f32x4 acc[4];
#pragma unroll
    for (int t = 0; t < 4; t++) acc[t] = {0.f, 0.f, 0.f, 0.f};
#pragma unroll
    for (int ks = 0; ks < 4; ks++) {
        short8 af = *(const short8*)&xs[(rw * 16 + l15) * 136 + ks * 32 + quad * 8];
#pragma unroll
        for (int t = 0; t < 4; t++) {
            short8 bf = *(const short8*)&wsb[((ch * 4 + t) * 16 + l15) * 136 + ks * 32 + quad * 8];
            acc[t] = __builtin_amdgcn_mfma_f32_16x16x32_bf16(af, bf, acc[t], 0, 0, 0);
        }
    }

    // epilogue: bias+relu, s1/s2 row dots (scaled by log2e), reduce over l15
    float s1p[4] = {0.f, 0.f, 0.f, 0.f}, s2p[4] = {0.f, 0.f, 0.f, 0.f};
#pragma unroll
    for (int t = 0; t < 4; t++) {
        int colg = (ch * 4 + t) * 16 + l15;
        float bgf = bF[layer * 128 + colg];
        float a1 = aF[layer * 256 + colg] * LOG2E;
        float a2 = aF[layer * 256 + 128 + colg] * LOG2E;
#pragma unroll
        for (int r = 0; r < 4; r++) {
            float v = acc[t][r] + bgf;
            v = v > 0.f ? v : 0.f;
            acc[t][r] = v;
            s1p[r] = fmaf(v, a1, s1p[r]);
            s2p[r] = fmaf(v, a2, s2p[r]);
        }
    }
#pragma unroll
    for (int r = 0; r < 4; r++) {
#pragma unroll
        for (int off = 1; off < 16; off <<= 1) {
            s1p[r] += __shfl_xor(s1p[r], off, 64);
            s2p[r] += __shfl_xor(s2p[r], off, 64);
        }
    }
    if (l15 == 0) {
#pragma unroll
        for (int r = 0; r < 4; r++) {
            int rloc = rw * 16 + quad * 4 + r;
            s12[0][ch][rloc] = s1p[r];
            s12[1][ch][rloc] = s2p[r];
        }
    }
    __syncthreads();                  // all MFMA reads of wsb done; s12 visible

    short* st = (short*)wsb;          // transpose buffer (64 rows x stride 130)
#pragma unroll
    for (int t = 0; t < 4; t++)
#pragma unroll
        for (int r = 0; r < 4; r++)
            st[(rw * 16 + quad * 4 + r) * 130 + (ch * 4 + t) * 16 + l15] = (short)f2bf(acc[t][r]);

    if (tid < 64) {                   // wave 0: combine col-halves, batch max
        float s1 = s12[0][0][tid] + s12[0][1][tid];
        float s2 = s12[1][0][tid] + s12[1][1][tid];
        s1g[row0 + tid] = s1;
        s2g[row0 + tid] = s2;
        float mx = s2;
#pragma unroll
        for (int off = 1; off < 64; off <<= 1)
            mx = fmaxf(mx, __shfl_xor(mx, off, 64));
        if (tid == 0) atomicMax(&s2mx[layer * 8 + b], fenc(mx));
    }
    __syncthreads();
    int jt0 = rg * 4;
    for (int c = tid; c < 1024; c += 512) {           // 4 t x 4 jt x 64 lanes
        int t = c >> 8, jl2 = (c >> 6) & 3, sl = c & 63;
        int d = t * 32 + (sl & 31);
        int jloc = jl2 * 16 + (sl >> 5) * 8;
        short8 o;
#pragma unroll
        for (int i = 0; i < 8; i++) o[i] = st[(jloc + i) * 130 + d];
        *(short8*)&hP[(((size_t)(b * 4 + t) * 128 + (jt0 + jl2)) * 64 + sl) * 8] = o;
    }
}

// ---- per layer: flash P@H via 32x32x16 MFMA with LDS P-sharing --------------
// Per iteration jl: wave w computes P fragment for jt=4*jl+w (8 exps), shares
// via double-buffered LDS; each wave owns output col-block t=w with a FULL-sum
// accumulator (no cross-wave acc reduce). Mask+pack: cvt_pk_bf16 + LDS LUT.
#define GAT_STEP(JL, CUR, NXT)                                                  \
  {                                                                             \
    unsigned b8 = (unsigned)(wdv[CUR] >> joff) & 0xffu;                         \
    float pv[8];                                                                \
    _Pragma("unroll")                                                           \
    for (int jj = 0; jj < 4; jj++) {                                            \
      float v0 = s1fold + sA[CUR][jj];                                          \
      float v1 = s1fold + sB[CUR][jj];                                          \
      pv[jj]     = __builtin_amdgcn_exp2f(fmaxf(v0, fmaf(0.2f, v0, c8)));       \
      pv[jj + 4] = __builtin_amdgcn_exp2f(fmaxf(v1, fmaf(0.2f, v1, c8)));       \
    }                                                                           \
    uint4v pk;                                                                  \
    pk[0] = cvt_pk_bf16(pv[0], pv[1]) & lutq[0][b8];                            \
    pk[1] = cvt_pk_bf16(pv[2], pv[3]) & lutq[1][b8];                            \
    pk[2] = cvt_pk_bf16(pv[4], pv[5]) & lutq[2][b8];                            \
    pk[3] = cvt_pk_bf16(pv[6], pv[7]) & lutq[3][b8];                            \
    short8 af = *(short8*)&pk;                                                  \
    *(short8*)&pshare[CUR][w][lane * 8] = af;                                   \
    ps = __builtin_amdgcn_mfma_f32_32x32x16_bf16(af, onesf, ps, 0, 0, 0);       \
    if ((JL) + 1 < 32) {                                                        \
      wdv[NXT] = prow[(JL) + 1];                                                \
      int j0n = ((JL) + 1) * 64 + joff;                                         \
      sA[NXT] = *(const f32x4*)&s2gb[j0n];                                      \
      sB[NXT] = *(const f32x4*)&s2gb[j0n + 4];                                  \
      _Pragma("unroll")                                                         \
      for (int q = 0; q < 4; q++)                                               \
        bfr[NXT][q] = *(const short8*)&hPb[((size_t)(w * 128 + ((JL) + 1) * 4 + q) * 64 + lane) * 8]; \
    }                                                                           \
    __syncthreads();                                                            \
    _Pragma("unroll")                                                           \
    for (int q = 0; q < 4; q++) {                                               \
      short8 pf = *(short8*)&pshare[CUR][q][lane * 8];                          \
      acc = __builtin_amdgcn_mfma_f32_32x32x16_bf16(pf, bfr[CUR][q], acc, 0, 0, 0); \
    }                                                                           \
  }

__global__ __launch_bounds__(256) void k_attn(
    const unsigned long long* __restrict__ packed,
    const unsigned short* __restrict__ hP, const float* __restrict__ s1g,
    const float* __restrict__ s2g, const unsigned* __restrict__ s2mx,
    int layer, float* __restrict__ xq)
{
    __shared__ unsigned lutq[4][256];            // bit-pair -> bf16-pair mask
    __shared__ short pshare[2][4][512];          // dbuf P fragments, 8 KB
    __shared__ float red_p[4][32];               // psum partials
    int blk = blockIdx.x, tid = threadIdx.x;
    int b = blk & 7, rg = blk >> 3;              // XCD swizzle: batch = blk%8
    int rowg0 = b * 2048 + rg * 32;
    int w = tid >> 6, lane = tid & 63;
    int col = lane & 31, khalf = lane >> 5;

    {                                            // build mask LUT (4 KB)
        unsigned e = (unsigned)tid;
#pragma unroll
        for (int q = 0; q < 4; q++)
            lutq[q][e] = (((e >> (2 * q)) & 1u) ? 0xffffu : 0u) |
                         (((e >> (2 * q + 1)) & 1u) ? 0xffff0000u : 0u);
    }

    float s1v = s1g[rowg0 + col];                // pre-scaled by log2e
    float s2m = fdec(s2mx[layer * 8 + b]);
    float tmh = s1v + s2m;
    float mhat = fmaxf(tmh, 0.2f * tmh);         // log2e * leaky(s1 + max s2)
    float s1fold = s1v - mhat;                   // fold -mhat into row const
    float c8 = -0.8f * mhat;                     // leaky branch: 0.2v - 0.8mhat

    short8 onesf;                                // B col 0 = 1.0 -> row-sum
    {
        short v = (col == 0) ? (short)0x3F80 : (short)0;
        onesf[0]=v;onesf[1]=v;onesf[2]=v;onesf[3]=v;onesf[4]=v;onesf[5]=v;onesf[6]=v;onesf[7]=v;
    }

    const float* s2gb = s2g + b * 2048;
    const unsigned short* hPb = hP + (size_t)b * 4 * 128 * 64 * 8;
    const unsigned long long* prow = packed + (size_t)(rowg0 + col) * 32;
    int joff = w * 16 + khalf * 8;               // bit offset & j offset

    f32x16 acc, ps;
#pragma unroll
    for (int r = 0; r < 16; r++) { acc[r] = 0.f; ps[r] = 0.f; }

    unsigned long long wdv[2];
    f32x4 sA[2], sB[2];
    short8 bfr[2][4];

    wdv[0] = prow[0];                            // prologue loads for jl=0
    sA[0] = *(const f32x4*)&s2gb[joff];
    sB[0] = *(const f32x4*)&s2gb[joff + 4];
#pragma unroll
    for (int q = 0; q < 4; q++)
        bfr[0][q] = *(const short8*)&hPb[((size_t)(w * 128 + q) * 64 + lane) * 8];
    __syncthreads();                             // LUT visible

#pragma unroll 1
    for (int jl = 0; jl < 32; jl += 2) {
        GAT_STEP(jl, 0, 1)
        GAT_STEP(jl + 1, 1, 0)
    }

    // psum cross-wave reduce (tiny); each wave normalizes+writes its col block
#pragma unroll
    for (int reg = 0; reg < 16; reg++) {
        int row = (reg & 3) + 8 * (reg >> 2) + 4 * khalf;
        if (col == 0) red_p[w][row] = ps[reg];
    }
    __syncthreads();
#pragma unroll
    for (int reg = 0; reg < 16; reg++) {
        int row = (reg & 3) + 8 * (reg >> 2) + 4 * khalf;
        float p = red_p[0][row] + red_p[1][row] + red_p[2][row] + red_p[3][row];
        float rl = p > 0.f ? __builtin_amdgcn_rcpf(p) : 0.f;
        xq[(rowg0 + row) * 128 + w * 32 + col] += acc[reg] * rl;
    }
}

extern "C" void kernel_launch(void* const* d_in, const int* in_sizes, int n_in,
                              void* d_out, int out_size, void* d_ws, size_t ws_size,
                              hipStream_t stream) {
    // adj = largest input; among the rest (excluding x = d_in[0]): W > attn_a > bg
    const void* px = d_in[0];
    int ia = 1; long amax = -1;
    for (int i = 1; i < n_in; i++)
        if ((long)in_sizes[i] > amax) { amax = in_sizes[i]; ia = i; }
    int rem[8]; int m = 0;
    for (int i = 1; i < n_in && m < 8; i++) if (i != ia) rem[m++] = i;
    for (int i = 0; i < m; i++)
        for (int j = i + 1; j < m; j++)
            if (in_sizes[rem[j]] > in_sizes[rem[i]]) { int t = rem[i]; rem[i] = rem[j]; rem[j] = t; }
    const int*   padj = (const int*)((n_in > 1) ? d_in[ia] : d_in[0]);
    const float* pW = (const float*)((m > 0) ? d_in[rem[0]] : d_in[0]);
    const float* pa = (const float*)((m > 1) ? d_in[rem[1]] : d_in[0]);
    const float* pb = (const float*)((m > 2) ? d_in[rem[2]] : d_in[0]);

    float* xq = (float*)d_out;                        // running fp32 x = output
    char* ws = (char*)d_ws;
    unsigned long long* packed = (unsigned long long*)ws;   // 4 MiB bitmask
    unsigned short* hP = (unsigned short*)(ws + 4194304);   // 4 MiB packed bf16 H
    float* s1 = (float*)(ws + 8388608);                     // 64 KiB (scaled)
    float* s2 = (float*)(ws + 8454144);                     // 64 KiB (scaled)
    unsigned* s2mx = (unsigned*)(ws + 8519680);             // 24 slots
    unsigned short* wTb = (unsigned short*)(ws + 8519808);  // 96 KiB bf16 W^T

    k_setup<<<4289, 256, 0, stream>>>((const float*)px, pW, padj, xq, wTb, s2mx, packed);
    for (int l = 0; l < 3; l++) {
        k_h<<<256, 512, 0, stream>>>(xq, wTb, pb, pa, l, hP, s1, s2, s2mx);
        k_attn<<<512, 256, 0, stream>>>(packed, hP, s1, s2, s2mx, l, xq);
    }
}